// Round 10
// baseline (382.800 us; speedup 1.0000x reference)
//
#include <hip/hip_runtime.h>
#include <math.h>

// ---------------------------------------------------------------------------
// Fastformer encoder layer — Round 10: 32x32x16 MFMA + L2-aware block swizzle
// on the proven R7/R9 GEMM structure (LDS-dbuf A + fragment-linear direct B).
//
// R9 post-mortem: launch_bounds(256,4) didn't raise residency (reg boundary);
// GEMM pinned ~900 TF, FETCH 3x ideal (L2 thrash from dispatch interleave).
// R10:
//  * mfma_f32_32x32x16_f16: 2495 vs 2176 TF ubench (m119) -> -17% MFMA pipe
//    cycles for identical FLOPs; half the MFMA instruction count.
//    Fragment maps: A/B lane L -> row/col = L&31, k = (L>>5)*8+j;
//    C/D: col = L&31, row = (r&3) + 8*(r>>2) + 4*(L>>5), r in [0,16).
//  * 1D grid + 64-block swizzle groups (8 m-tiles x 8 n-tiles): with
//    bid%8 -> XCD round-robin, per-XCD resident set ~2.3MB < 4MB L2.
// ws: h16@0(16M) | kv16/act16@16M(32M overlay) | vq@48M(16M) |
//     swizzled weights@64M(18M) | gk@82M
// ---------------------------------------------------------------------------

#define DM     1024
#define FFH    2048
#define M_TOT  8192

typedef _Float16 f16x8  __attribute__((ext_vector_type(8)));
typedef float    f32x16 __attribute__((ext_vector_type(16)));

__device__ __forceinline__ void gl2lds16(const void* g, void* l) {
    __builtin_amdgcn_global_load_lds(
        (const __attribute__((address_space(1))) void*)g,
        (__attribute__((address_space(3))) void*)l, 16, 0, 0);
}
__device__ __forceinline__ unsigned short f2h(float x) {
    union { _Float16 h; unsigned short u; } c;
    c.h = (_Float16)x;
    return c.u;
}
__device__ __forceinline__ float h2f(unsigned short u) {
    union { unsigned short u; _Float16 h; } c;
    c.u = u;
    return (float)c.h;
}

// ---------------------------------------------------------------------------
// weight cast fp32 -> fp16 fragment-linear for 32x32x16:
// chunk i = (ntile*KT + kt)*64 + lane ; lane L holds
// W[nt*32 + (L&31)][kt*16 + (L>>5)*8 .. +8].  KT = K/16.
// ---------------------------------------------------------------------------
__global__ __launch_bounds__(256) void wcast_sw(
    const float* __restrict__ s0, const float* __restrict__ s1,
    const float* __restrict__ s2, const float* __restrict__ s3,
    unsigned short* __restrict__ d0, unsigned short* __restrict__ d1,
    unsigned short* __restrict__ d2, unsigned short* __restrict__ d3)
{
    int i = blockIdx.x * 256 + threadIdx.x;
    const float* s; unsigned short* d; int kl;   // kl = log2(KT)
    if      (i < 262144) {               s = s0; d = d0; kl = 6; }
    else if (i < 393216) { i -= 262144;  s = s1; d = d1; kl = 6; }
    else if (i < 917504) { i -= 393216;  s = s2; d = d2; kl = 6; }
    else                 { i -= 917504;  s = s3; d = d3; kl = 7; }
    const int lane = i & 63, tile = i >> 6;
    const int kt = tile & ((1 << kl) - 1), nt = tile >> kl;
    const int K  = 16 << kl;
    const int row = nt * 32 + (lane & 31);
    const int col = kt * 16 + (lane >> 5) * 8;
    const float* src = s + (size_t)row * K + col;
    const float4 v0 = ((const float4*)src)[0];
    const float4 v1 = ((const float4*)src)[1];
    ushort4 h0, h1;
    h0.x = f2h(v0.x); h0.y = f2h(v0.y); h0.z = f2h(v0.z); h0.w = f2h(v0.w);
    h1.x = f2h(v1.x); h1.y = f2h(v1.y); h1.z = f2h(v1.z); h1.w = f2h(v1.w);
    unsigned short* dst = d + (size_t)i * 8;
    *(ushort4*)dst       = h0;
    *(ushort4*)(dst + 4) = h1;
}

// ---------------------------------------------------------------------------
// LayerNorm -> fp16 row-major (validated R3-R9).
// ---------------------------------------------------------------------------
__global__ __launch_bounds__(256) void ln_f16(
    const float* __restrict__ x, const float* __restrict__ g,
    const float* __restrict__ b, unsigned short* __restrict__ y)
{
    const int row = blockIdx.x;
    const int t   = threadIdx.x;
    const float4 v = ((const float4*)(x + (size_t)row * DM))[t];

    float s  = v.x + v.y + v.z + v.w;
    float ss = v.x * v.x + v.y * v.y + v.z * v.z + v.w * v.w;
    #pragma unroll
    for (int off = 32; off > 0; off >>= 1) {
        s  += __shfl_xor(s, off);
        ss += __shfl_xor(ss, off);
    }
    __shared__ float sm[8];
    const int wave = t >> 6;
    if ((t & 63) == 0) { sm[wave * 2] = s; sm[wave * 2 + 1] = ss; }
    __syncthreads();
    s  = sm[0] + sm[2] + sm[4] + sm[6];
    ss = sm[1] + sm[3] + sm[5] + sm[7];

    const float mu  = s * (1.0f / DM);
    const float var = ss * (1.0f / DM) - mu * mu;
    const float r   = rsqrtf(var + 1e-5f);

    const float4 gv = ((const float4*)g)[t];
    const float4 bv = ((const float4*)b)[t];
    ushort4 o;
    o.x = f2h((v.x - mu) * r * gv.x + bv.x);
    o.y = f2h((v.y - mu) * r * gv.y + bv.y);
    o.z = f2h((v.z - mu) * r * gv.z + bv.z);
    o.w = f2h((v.w - mu) * r * gv.w + bv.w);
    ((ushort4*)(y + (size_t)row * DM))[t] = o;
}

// ---------------------------------------------------------------------------
// attention (R9, validated): chain-free sums, 128 blocks (b,h).
// ---------------------------------------------------------------------------
__global__ __launch_bounds__(256) void attn_gk(
    const unsigned short* __restrict__ kv, const float* __restrict__ kw,
    float* __restrict__ gk)
{
    const int bh = blockIdx.x;
    const int b = bh >> 4, h = bh & 15;
    const int t = threadIdx.x, e = t & 63, w = t >> 6;
    const unsigned short* kp =
        kv + (size_t)b * 1024 * 2048 + (size_t)(w * 256) * 2048 + h * 64 + e;
    const float* kwr = kw + h * 1024 + w * 256;

    float l = 0.f, s = 0.f;
    #pragma unroll 8
    for (int i = 0; i < 256; ++i) {
        const float kval = h2f(kp[(size_t)i * 2048]);
        const float ex   = __expf(kval * kwr[i] * 0.125f);
        l += ex;
        s += ex * kval;
    }
    __shared__ float sl[256], sv[256];
    sl[t] = l; sv[t] = s;
    __syncthreads();
    if (t < 64) {
        #pragma unroll
        for (int ww = 1; ww < 4; ++ww) {
            l += sl[ww * 64 + e];
            s += sv[ww * 64 + e];
        }
        gk[(size_t)b * DM + h * 64 + e] = s / l;
    }
}

// ---------------------------------------------------------------------------
// v-scale (validated): vq[m][d] = fp16( v16[m][d] * gk[batch][d] ).
// ---------------------------------------------------------------------------
__global__ __launch_bounds__(256) void vscale_f16(
    const unsigned short* __restrict__ kv, const float* __restrict__ gk,
    unsigned short* __restrict__ vq)
{
    const int m = blockIdx.x;
    const int t = threadIdx.x;
    const int b = m >> 10;
    const ushort4 v4 = *(const ushort4*)(kv + (size_t)m * 2048 + 1024 + t * 4);
    const float4  s4 = *(const float4*)(gk + b * DM + t * 4);
    ushort4 o;
    o.x = f2h(h2f(v4.x) * s4.x);
    o.y = f2h(h2f(v4.y) * s4.y);
    o.z = f2h(h2f(v4.z) * s4.z);
    o.w = f2h(h2f(v4.w) * s4.w);
    *(ushort4*)(vq + (size_t)m * DM + t * 4) = o;
}

// ---------------------------------------------------------------------------
// fp16 MFMA GEMM, 32x32x16 frags. 256 thr = 4 waves (2x2 wm x wn), block
// tile 128x128 (LIN1ACT: 128 x 64 out cols; wn=0 a, wn=1 g). Wave 64x64 =
// 2x2 of 32x32 frags, acc 2x2xf32x16 = 64 AGPR.
// A: global_load_lds row-major, 2x16KB dbuf, chunk-XOR swizzle.
// B: fragment-linear (wcast_sw), coalesced direct-to-reg, k32 ping-pong.
// 1D grid, 64-block swizzle groups (8 m x 8 n tiles) for per-XCD L2 fit.
// OUTM: 0 fp16 out, 2 fp32 out + residual.
// ---------------------------------------------------------------------------
template <bool LIN1ACT, int OUTM>
__global__ __launch_bounds__(256, 3) void fgemm(
    const unsigned short* __restrict__ A,
    const unsigned short* __restrict__ Bsw,
    const float* __restrict__ bias,
    const float* __restrict__ residual,
    float* __restrict__ Cf, unsigned short* __restrict__ Cq,
    int K, int lda, int ldc, int gridx)
{
    __shared__ __align__(16) char lds[32768];   // 2x16KB A stages / 16KB xch

    // --- block swizzle: groups of 64 = 8 m-tiles x 8 n-tiles -------------
    const int bid = blockIdx.x;
    const int gid = bid >> 6, sub = bid & 63;
    const int gPerRow = gridx >> 3;              // >=1 for all our grids
    const int gy = gid / gPerRow, gx = gid - gy * gPerRow;
    const int by = gy * 8 + (sub >> 3);
    const int bx = gx * 8 + (sub & 7);

    const int t  = threadIdx.x;
    const int m0 = by * 128;
    const int n0 = bx * (LIN1ACT ? 64 : 128);
    const int L  = t & 63, w = t >> 6;
    const int wm = w >> 1, wn = w & 1;
    const int c32 = L & 31, rh = L >> 5;
    const int KT = K >> 4;                       // 16-wide k-tiles

    // A staging: 1024 chunks/stage, 4 per thread; c = t + j*256,
    // row = c>>3 (0..127), chunk-in-row = (c&7)^(row&7).
    const int arow = t >> 3;
    const int ach  = (t & 7) ^ (arow & 7);
    const unsigned short* pA0 = A + (size_t)(m0 + arow) * lda + ach * 8;
    const int ldst0 = t * 16;

    // B fragment-linear bases: wave covers 64 cols = 2 ntiles of 32.
    const int bcol0 = LIN1ACT ? ((wn ? FFH : 0) + n0) : (n0 + wn * 64);
    const unsigned short* pB[2];
    #pragma unroll
    for (int ni = 0; ni < 2; ++ni)
        pB[ni] = Bsw + (size_t)((bcol0 >> 5) + ni) * KT * 512 + L * 8;

    f32x16 acc[2][2];
    #pragma unroll
    for (int i = 0; i < 2; ++i)
        #pragma unroll
        for (int j = 0; j < 2; ++j)
            #pragma unroll
            for (int r = 0; r < 16; ++r) acc[i][j][r] = 0.f;

    // A-frag LDS byte offsets: frag (mi, hk) hk=0..3 (16-k sub-tiles of the
    // 64-k stage): row = wm*64+mi*32+c32, chunk = (hk*2+rh)^(row&7).
    int aoff[2][4];
    #pragma unroll
    for (int mi = 0; mi < 2; ++mi) {
        const int row = wm * 64 + mi * 32 + c32;
        #pragma unroll
        for (int hk = 0; hk < 4; ++hk)
            aoff[mi][hk] = row * 128 + (((hk * 2 + rh) ^ (row & 7)) * 16);
    }

    // prologue: A stage 0 -> buf0; B frags kt 0,1 -> b0
    #pragma unroll
    for (int j = 0; j < 4; ++j)
        gl2lds16(pA0 + (size_t)j * 32 * lda, lds + ldst0 + j * 4096);
    f16x8 b0[4], b1[4];                          // [ni*2+ktl]
    #pragma unroll
    for (int ni = 0; ni < 2; ++ni)
        #pragma unroll
        for (int ktl = 0; ktl < 2; ++ktl)
            b0[ni * 2 + ktl] = *(const f16x8*)(pB[ni] + (size_t)ktl * 512);
    __syncthreads();

    int p = 0;
    for (int k0 = 0; k0 < K; k0 += 64) {
        const int kt0  = k0 >> 4;
        const int kpre = (k0 + 64 < K) ? k0 + 64 : 0;
        #pragma unroll
        for (int j = 0; j < 4; ++j)
            gl2lds16(pA0 + (size_t)j * 32 * lda + kpre,
                     lds + (p ^ 1) * 16384 + ldst0 + j * 4096);
        // prefetch half1 B frags (kt0+2, kt0+3)
        #pragma unroll
        for (int ni = 0; ni < 2; ++ni)
            #pragma unroll
            for (int ktl = 0; ktl < 2; ++ktl)
                b1[ni * 2 + ktl] =
                    *(const f16x8*)(pB[ni] + (size_t)(kt0 + 2 + ktl) * 512);

        // half0 compute
        f16x8 af[2][2];
        #pragma unroll
        for (int mi = 0; mi < 2; ++mi)
            #pragma unroll
            for (int ktl = 0; ktl < 2; ++ktl)
                af[mi][ktl] = *(const f16x8*)(lds + p * 16384 + aoff[mi][ktl]);
        #pragma unroll
        for (int ktl = 0; ktl < 2; ++ktl)
            #pragma unroll
            for (int mi = 0; mi < 2; ++mi)
                #pragma unroll
                for (int ni = 0; ni < 2; ++ni)
                    acc[mi][ni] = __builtin_amdgcn_mfma_f32_32x32x16_f16(
                        af[mi][ktl], b0[ni * 2 + ktl], acc[mi][ni], 0, 0, 0);

        // prefetch next-stage half0 B frags (kt0+4, kt0+5; wrap at tail)
        const int ktn = (kt0 + 4 < KT) ? kt0 + 4 : 0;
        #pragma unroll
        for (int ni = 0; ni < 2; ++ni)
            #pragma unroll
            for (int ktl = 0; ktl < 2; ++ktl)
                b0[ni * 2 + ktl] =
                    *(const f16x8*)(pB[ni] + (size_t)(ktn + ktl) * 512);

        // half1 compute
        #pragma unroll
        for (int mi = 0; mi < 2; ++mi)
            #pragma unroll
            for (int ktl = 0; ktl < 2; ++ktl)
                af[mi][ktl] =
                    *(const f16x8*)(lds + p * 16384 + aoff[mi][2 + ktl]);
        #pragma unroll
        for (int ktl = 0; ktl < 2; ++ktl)
            #pragma unroll
            for (int mi = 0; mi < 2; ++mi)
                #pragma unroll
                for (int ni = 0; ni < 2; ++ni)
                    acc[mi][ni] = __builtin_amdgcn_mfma_f32_32x32x16_f16(
                        af[mi][ktl], b1[ni * 2 + ktl], acc[mi][ni], 0, 0, 0);

        __syncthreads();
        p ^= 1;
    }

    // C/D mapping: col = c32, row32 = (r&3) + 8*(r>>2) + 4*rh
    if (!LIN1ACT) {
        #pragma unroll
        for (int mi = 0; mi < 2; ++mi)
            #pragma unroll
            for (int ni = 0; ni < 2; ++ni) {
                const int gcol = n0 + wn * 64 + ni * 32 + c32;
                const float bc = bias[gcol];
                #pragma unroll
                for (int r = 0; r < 16; ++r) {
                    const int grow = m0 + wm * 64 + mi * 32 +
                                     (r & 3) + ((r >> 2) << 3) + (rh << 2);
                    float v = acc[mi][ni][r] + bc;
                    if (OUTM == 2) {
                        v += residual[(size_t)grow * ldc + gcol];
                        Cf[(size_t)grow * ldc + gcol] = v;
                    } else {
                        Cq[(size_t)grow * ldc + gcol] = f2h(v);
                    }
                }
            }
    } else {
        unsigned short* xch = (unsigned short*)lds;   // [128][64] fp16 = 16KB
        if (wn == 1) {
            #pragma unroll
            for (int mi = 0; mi < 2; ++mi)
                #pragma unroll
                for (int ni = 0; ni < 2; ++ni) {
                    const int col = ni * 32 + c32;
                    const float bg = bias[FFH + n0 + col];
                    #pragma unroll
                    for (int r = 0; r < 16; ++r) {
                        const int row = wm * 64 + mi * 32 +
                                        (r & 3) + ((r >> 2) << 3) + (rh << 2);
                        xch[row * 64 + col] =
                            f2h(fmaxf(acc[mi][ni][r] + bg, 0.f));
                    }
                }
        }
        __syncthreads();
        if (wn == 0) {
            #pragma unroll
            for (int mi = 0; mi < 2; ++mi)
                #pragma unroll
                for (int ni = 0; ni < 2; ++ni) {
                    const int col = ni * 32 + c32;
                    const float ba = bias[n0 + col];
                    #pragma unroll
                    for (int r = 0; r < 16; ++r) {
                        const int row = wm * 64 + mi * 32 +
                                        (r & 3) + ((r >> 2) << 3) + (rh << 2);
                        const float a = acc[mi][ni][r] + ba;
                        const float o = a * h2f(xch[row * 64 + col]);
                        Cq[(size_t)(m0 + row) * FFH + n0 + col] = f2h(o);
                    }
                }
        }
    }
}

// ---------------------------------------------------------------------------
extern "C" void kernel_launch(void* const* d_in, const int* in_sizes, int n_in,
                              void* d_out, int out_size, void* d_ws, size_t ws_size,
                              hipStream_t stream)
{
    const float* hidden = (const float*)d_in[0];
    const float* qkv_w  = (const float*)d_in[2];
    const float* qkv_b  = (const float*)d_in[3];
    const float* out_w  = (const float*)d_in[4];
    const float* out_b  = (const float*)d_in[5];
    const float* key_w  = (const float*)d_in[7];
    const float* n1g    = (const float*)d_in[8];
    const float* n1b    = (const float*)d_in[9];
    const float* n2g    = (const float*)d_in[10];
    const float* n2b    = (const float*)d_in[11];
    const float* l1w    = (const float*)d_in[12];
    const float* l1b    = (const float*)d_in[13];
    const float* l2w    = (const float*)d_in[14];
    const float* l2b    = (const float*)d_in[15];
    float* out = (float*)d_out;
    char*  wsb = (char*)d_ws;

    const size_t MB = 1u << 20;
    unsigned short* h16    = (unsigned short*)wsb;               // 16 MB
    unsigned short* kv16   = (unsigned short*)(wsb + 16 * MB);   // 32 MB
    unsigned short* act16  = (unsigned short*)(wsb + 16 * MB);   // overlay
    unsigned short* vq     = (unsigned short*)(wsb + 48 * MB);   // 16 MB
    unsigned short* wkv_sw = (unsigned short*)(wsb + 64 * MB);   // 4 MB
    unsigned short* wo_sw  = (unsigned short*)(wsb + 68 * MB);   // 2 MB
    unsigned short* l1_sw  = (unsigned short*)(wsb + 70 * MB);   // 8 MB
    unsigned short* l2_sw  = (unsigned short*)(wsb + 78 * MB);   // 4 MB
    float*          gk     = (float*)(wsb + 82 * MB);            // 32 KB

    // 0. weights -> fp16 fragment-linear (32x32x16 layout)
    wcast_sw<<<4608, 256, 0, stream>>>(
        qkv_w + (size_t)DM * DM, out_w, l1w, l2w,
        wkv_sw, wo_sw, l1_sw, l2_sw);

    // 1. h1 = LN1(hidden) -> fp16
    ln_f16<<<M_TOT, 256, 0, stream>>>(hidden, n1g, n1b, h16);

    // 2. kv16 = fp16( h1 @ Wkv^T + b )  (ldc 2048), 1024 blocks (GX=16)
    fgemm<false, 0><<<1024, 256, 0, stream>>>(
        h16, wkv_sw, qkv_b + DM, nullptr, nullptr, kv16, 1024, 1024, 2048, 16);

    // 3. global_key
    attn_gk<<<128, 256, 0, stream>>>(kv16, key_w, gk);

    // 4. vq = fp16(v * gk)
    vscale_f16<<<M_TOT, 256, 0, stream>>>(kv16, gk, vq);

    // 5. hidden2 = hidden + vq @ out_w^T + out_b -> d_out, 512 blocks (GX=8)
    fgemm<false, 2><<<512, 256, 0, stream>>>(
        vq, wo_sw, out_b, hidden, out, nullptr, 1024, 1024, 1024, 8);

    // 6. h2 = LN2(hidden2) -> fp16
    ln_f16<<<M_TOT, 256, 0, stream>>>(out, n2g, n2b, h16);

    // 7. act16 = fp16( (h2@W_a^T+b_a) * relu(h2@W_g^T+b_g) ), 2048 blk (GX=32)
    fgemm<true, 0><<<2048, 256, 0, stream>>>(
        h16, l1_sw, l1b, nullptr, nullptr, act16, 1024, 1024, 0, 32);

    // 8. out = hidden2 + act @ l2w^T + l2b (in-place residual), 512 blk (GX=8)
    fgemm<false, 2><<<512, 256, 0, stream>>>(
        act16, l2_sw, l2b, out, out, nullptr, 2048, 2048, 1024, 8);
}